// Round 7
// baseline (86.854 us; speedup 1.0000x reference)
//
#include <hip/hip_runtime.h>
#include <hip/hip_bf16.h>

// Problem constants
#define BATCH 2
#define NPTS 2048
#define NCH 64
#define IMG 128
#define KTOP 8
#define BIGF 1e10f
#define CAP 128     // per-row candidate capacity (expected ~48; 11 sigma margin)
#define FPITCH 68   // feature row pitch in floats: 16B-aligned, spreads b128 banks

// ---------------------------------------------------------------------------
// Kernel 1: fused prep (identical to R5's, which passed).
// blocks [0,64): transpose src [B,C,P] -> srcT [B,P,C] (coalesced both ways).
// blocks [64,128): per-row binning, one wave per (b,h) row, ballot-compacted:
// deterministic, atomic-free; list preserves point-index order, so a stable
// strict-z insertion later reproduces top_k's lowest-index tie-break.
// ---------------------------------------------------------------------------
__global__ __launch_bounds__(256) void prep(
    const float* __restrict__ pts,   // [B, P, 3]
    const float* __restrict__ src,   // [B, C, P]
    float* __restrict__ srcT,        // [B, P, C]
    float4* __restrict__ bins,       // [B*IMG, CAP] (x, y, z, idx_bits)
    int* __restrict__ counts) {      // [B*IMG]
  const int blk = blockIdx.x;
  if (blk < 64) {
    __shared__ float tile[64][65];  // +1 pad: conflict-free
    int b = blk >> 5;
    int p0 = (blk & 31) << 6;
    int tx = threadIdx.x & 63;
    int ty = threadIdx.x >> 6;
    const float* s = src + b * NCH * NPTS;
    #pragma unroll
    for (int cc = 0; cc < 64; cc += 4) {
      int c = cc + ty;
      tile[tx][c] = s[c * NPTS + p0 + tx];  // coalesced over tx
    }
    __syncthreads();
    float* dT = srcT + (b * NPTS + p0) * NCH;
    #pragma unroll
    for (int pp = 0; pp < 64; pp += 4) {
      int p = pp + ty;
      dT[p * NCH + tx] = tile[p][tx];       // coalesced over tx
    }
  } else {
    const int wave = threadIdx.x >> 6;
    const int lane = threadIdx.x & 63;
    const int row = ((blk - 64) << 2) + wave;   // 0..255 = b*IMG + h
    const int b = row >> 7;
    const int h = row & 127;
    const float r_ndc = 0.0234375f;             // 3/128 exact
    const float r2 = r_ndc * r_ndc;
    const float yc = 1.0f - 2.0f * (h + 0.5f) / 128.0f;
    const float* pb = pts + b * NPTS * 3;
    float4* brow = bins + row * CAP;
    int base = 0;
    for (int it = 0; it < NPTS / 64; ++it) {    // 32 iterations
      int p = (it << 6) + lane;
      float y = pb[p * 3 + 1];
      float dy = yc + y;                        // reference's dy, bit-exact
      bool hit = (dy * dy <= r2);               // conservative superset of
                                                // dx^2+dy^2<=r2 (fp-safe)
      unsigned long long mask = __ballot(hit);
      int prefix = __popcll(mask & ((1ull << lane) - 1ull));
      if (hit) {
        int pos = base + prefix;
        if (pos < CAP)
          brow[pos] = make_float4(pb[p * 3 + 0], y, pb[p * 3 + 2],
                                  __int_as_float(p));
      }
      base += __popcll(mask);
    }
    if (lane == 0) counts[row] = min(base, CAP);
  }
}

// ---------------------------------------------------------------------------
// Kernel 2: raster + composite with coalesced LDS feature staging.
// Grid = B*IMG*2 = 512 blocks x 256 threads. Block = (b, h, half) = 64 px.
// Stage 1: load bin entries (coalesced float4).
// Stage 2: stage candidate feature rows srcT[b,p,:] into LDS — one wave per
//          row, lane = channel: fully coalesced 256B reads (this replaces the
//          per-lane scattered gathers that TA-serialized rounds 1-6).
// Stage 3: 4 waves redundantly compute per-pixel top-8 (lane = pixel),
//          stable strict-z insert on the p-ordered list, tracking LDS slot.
// Stage 4: weights + composite; each wave reads its 16-channel slice from
//          LDS (ds_read_b128, banks spread by FPITCH), coalesced stores.
// ---------------------------------------------------------------------------
__global__ __launch_bounds__(256) void raster(
    const float4* __restrict__ bins,  // [B*IMG, CAP]
    const int* __restrict__ counts,   // [B*IMG]
    const float* __restrict__ srcT,   // [B, P, C]
    float* __restrict__ out) {        // [B, C, H, W]
  __shared__ float4 cand[CAP];
  __shared__ float feat[CAP * FPITCH];

  const int bid = blockIdx.x;
  const int half = bid & 1;
  const int h = (bid >> 1) & 127;
  const int b = bid >> 8;
  const int tid = threadIdx.x;

  const int row = (b << 7) + h;
  const int cnt = min(counts[row], CAP);
  const float4* grow = bins + row * CAP;
  for (int j = tid; j < cnt; j += 256) cand[j] = grow[j];  // coalesced
  __syncthreads();

  // --- Stage 2: coalesced feature staging (wave j-row, lane = channel) ---
  const float* sT = srcT + (size_t)b * NPTS * NCH;
  for (int t = tid; t < cnt * NCH; t += 256) {
    int j = t >> 6;
    int c = t & 63;
    int p = __float_as_int(cand[j].w);
    feat[j * FPITCH + c] = sT[(size_t)p * NCH + c];  // contiguous 256B row
  }
  if (cnt == 0 && tid < NCH) feat[tid] = 0.0f;  // avoid NaN*0 from stale LDS
  __syncthreads();

  const float r_ndc = 0.0234375f;     // RADIUS/SIZE*2 = 3/128, exact
  const float r2 = r_ndc * r_ndc;     // exact: 9*2^-14
  const float yc = 1.0f - 2.0f * (h + 0.5f) / 128.0f;
  const int lane = tid & 63;
  const int w = (half << 6) + lane;
  const float xc = 1.0f - 2.0f * (w + 0.5f) / 128.0f;

  // --- Stage 3: top-8 by z asc; stable strict < == top_k order ---
  float bz[KTOP], bd[KTOP];
  int bj[KTOP];
  #pragma unroll
  for (int k = 0; k < KTOP; ++k) { bz[k] = BIGF; bd[k] = 0.f; bj[k] = 0; }

  for (int j = 0; j < cnt; ++j) {
    float4 c4 = cand[j];               // LDS broadcast (same addr all lanes)
    float dx = xc + c4.x;              // == xc - (-x), reference's dx
    float dyy = yc + c4.y;
    float d2 = dx * dx + dyy * dyy;
    if (d2 <= r2) {
      float cz = c4.z, cd = d2;
      int cj = j;
      #pragma unroll
      for (int s = 0; s < KTOP; ++s) {
        bool lt = (cz < bz[s]);        // strict: stability = index tie-break
        float tz = bz[s], td = bd[s];
        int tj = bj[s];
        if (lt) { bz[s] = cz; bd[s] = cd; bj[s] = cj;
                  cz = tz; cd = td; cj = tj; }
      }
    }
  }

  // --- Stage 4a: weights ---
  float wgt[KTOP];
  float T = 1.0f;
  const float inv_r2 = 1.0f / r2;
  #pragma unroll
  for (int k = 0; k < KTOP; ++k) {
    float alpha = 0.0f;
    if (bz[k] < BIGF) {
      float dist = bd[k] * inv_r2;
      dist = fminf(fmaxf(dist, 0.001f), 1.0f);
      alpha = 1.0f - sqrtf(dist);
    }
    wgt[k] = alpha * T;                // unfilled: bj=0 (staged row), wgt=0
    T *= (1.0f - alpha);
  }

  // --- Stage 4b: composite this wave's 16-channel slice from LDS ---
  const int cq0 = (tid >> 6) * 4;      // wave's float4-quad base
  const float4* f4 = (const float4*)feat;
  float4 acc[4];
  #pragma unroll
  for (int q = 0; q < 4; ++q) acc[q] = make_float4(0.f, 0.f, 0.f, 0.f);
  #pragma unroll
  for (int k = 0; k < KTOP; ++k) {
    float wk = wgt[k];
    int base = bj[k] * (FPITCH / 4) + cq0;
    #pragma unroll
    for (int q = 0; q < 4; ++q) {
      float4 v = f4[base + q];         // ds_read_b128
      acc[q].x += wk * v.x;
      acc[q].y += wk * v.y;
      acc[q].z += wk * v.z;
      acc[q].w += wk * v.w;
    }
  }

  float* ob = out + (((size_t)b * NCH + cq0 * 4) * IMG + h) * IMG + w;
  const int S = IMG * IMG;
  #pragma unroll
  for (int q = 0; q < 4; ++q) {
    ob[(q * 4 + 0) * S] = acc[q].x;    // coalesced over lanes (w)
    ob[(q * 4 + 1) * S] = acc[q].y;
    ob[(q * 4 + 2) * S] = acc[q].z;
    ob[(q * 4 + 3) * S] = acc[q].w;
  }
}

extern "C" void kernel_launch(void* const* d_in, const int* in_sizes, int n_in,
                              void* d_out, int out_size, void* d_ws, size_t ws_size,
                              hipStream_t stream) {
  const float* pts = (const float*)d_in[0];   // [B,P,3]
  const float* src = (const float*)d_in[1];   // [B,C,P]
  float* out = (float*)d_out;                 // [B,C,H,W]

  // ws layout: srcT (1 MB) | bins (512 KB) | counts (1 KB)
  char* ws = (char*)d_ws;
  float* srcT = (float*)ws;
  float4* bins = (float4*)(ws + (size_t)BATCH * NPTS * NCH * 4);
  int* counts = (int*)(ws + (size_t)BATCH * NPTS * NCH * 4 +
                       (size_t)BATCH * IMG * CAP * 16);

  prep<<<128, 256, 0, stream>>>(pts, src, srcT, bins, counts);
  raster<<<BATCH * IMG * 2, 256, 0, stream>>>(bins, counts, srcT, out);
}

// Round 8
// 84.945 us; speedup vs baseline: 1.0225x; 1.0225x over previous
//
#include <hip/hip_runtime.h>
#include <hip/hip_bf16.h>

// Problem constants
#define BATCH 2
#define NPTS 2048
#define NCH 64
#define IMG 128
#define KTOP 8
#define BIGF 1e10f
#define CAP 128   // per-row candidate capacity (expected ~48; CAP=128 passed R2-R7)

// ---------------------------------------------------------------------------
// Single megakernel (best measured config, R6): scan + top-8 + composite.
// No workspace, one dispatch node. Grid = B*IMG*2*4 = 4096 blocks x 64
// threads (1 wave, 2 KB LDS). Wave = (batch, row, half, 16-channel group);
// lane = pixel.
//
// Phase 1: ballot-compacted y-band scan of all 2048 points into LDS.
//          dy^2 <= r2 is a conservative superset of dx^2+dy^2 <= r2
//          (fl(a+b) >= b for a,b >= 0); dy computed bit-identically to the
//          reference (yc + y == yc - (-y)). Compaction preserves point-index
//          order, so a stable strict-z insertion reproduces top_k's
//          lowest-index tie-break.
// Phase 2: per-lane top-8 by z (stable insert), LDS reads prefetched one
//          iteration ahead to break the ds_read -> compare dependence.
// Phase 3: alpha = 1 - sqrt(clamp(d2/r^2, .001, 1)), front-to-back
//          transmittance; composite 16 channels directly from src [B,C,P]
//          (L1/L2-hit gathers, <=48 distinct points per row shared across
//          lanes); coalesced stores over lanes (w).
// ---------------------------------------------------------------------------
__global__ __launch_bounds__(64) void raster_mega(
    const float* __restrict__ pts,   // [B, P, 3]
    const float* __restrict__ src,   // [B, C, P]
    float* __restrict__ out) {       // [B, C, H, W]
  __shared__ float4 cand[CAP];       // (x, y, z, idx_bits), p-ordered

  const int bid = blockIdx.x;
  const int cg = bid & 3;            // 16-channel group
  const int half = (bid >> 2) & 1;
  const int h = (bid >> 3) & 127;
  const int b = bid >> 10;
  const int lane = threadIdx.x;

  const float r_ndc = 0.0234375f;    // RADIUS/SIZE*2 = 3/128, exact
  const float r2 = r_ndc * r_ndc;    // exact: 9*2^-14
  const float yc = 1.0f - 2.0f * (h + 0.5f) / 128.0f;

  // --- Phase 1: ballot-compacted scan into LDS (p-order preserved) ---
  const float* pb = pts + b * NPTS * 3;
  int base = 0;
  for (int it = 0; it < NPTS / 64; ++it) {   // 32 iterations
    int p = (it << 6) + lane;
    float y = pb[p * 3 + 1];                 // L1-hit (pts: 24 KB/batch)
    float dy = yc + y;                       // reference's dy, bit-exact
    bool hit = (dy * dy <= r2);
    unsigned long long mask = __ballot(hit);
    if (mask) {                              // wave-uniform branch
      if (hit) {
        int pos = base + __popcll(mask & ((1ull << lane) - 1ull));
        if (pos < CAP)
          cand[pos] = make_float4(pb[p * 3 + 0], y, pb[p * 3 + 2],
                                  __int_as_float(p));
      }
      base += __popcll(mask);
    }
  }
  __syncthreads();                           // 1 wave: just lgkmcnt drain
  const int cnt = min(base, CAP);

  const int w = (half << 6) + lane;
  const float xc = 1.0f - 2.0f * (w + 0.5f) / 128.0f;

  // --- Phase 2: top-8 by z asc; stable strict < == top_k order ---
  float bz[KTOP], bd[KTOP];
  int bp[KTOP];
  #pragma unroll
  for (int k = 0; k < KTOP; ++k) { bz[k] = BIGF; bd[k] = 0.f; bp[k] = 0; }

  float4 nxt = cand[0];                      // prefetch (safe: CAP-sized)
  for (int j = 0; j < cnt; ++j) {
    float4 c4 = nxt;
    int jn = (j + 1 < cnt) ? j + 1 : j;      // OOB-guarded prefetch
    nxt = cand[jn];
    float dx = xc + c4.x;                    // == xc - (-x), reference's dx
    float dyy = yc + c4.y;
    float d2 = dx * dx + dyy * dyy;
    if (d2 <= r2) {                          // rare per lane (~0.9 hits avg)
      float cz = c4.z, cd = d2;
      int cp = __float_as_int(c4.w);
      #pragma unroll
      for (int s = 0; s < KTOP; ++s) {
        bool lt = (cz < bz[s]);              // strict: stability = tie-break
        float tz = bz[s], td = bd[s];
        int tp = bp[s];
        if (lt) { bz[s] = cz; bd[s] = cd; bp[s] = cp;
                  cz = tz; cd = td; cp = tp; }
      }
    }
  }

  // --- Phase 3a: weights ---
  float wgt[KTOP];
  float T = 1.0f;
  const float inv_r2 = 1.0f / r2;
  #pragma unroll
  for (int k = 0; k < KTOP; ++k) {
    float alpha = 0.0f;
    if (bz[k] < BIGF) {
      float dist = bd[k] * inv_r2;
      dist = fminf(fmaxf(dist, 0.001f), 1.0f);
      alpha = 1.0f - sqrtf(dist);
    }
    wgt[k] = alpha * T;                      // unfilled: bp=0 (safe), wgt=0
    T *= (1.0f - alpha);
  }

  // --- Phase 3b: composite 16 channels straight from src [B,C,P] ---
  const float* sb = src + ((size_t)b * NCH + cg * 16) * NPTS;
  float acc[16];
  #pragma unroll
  for (int c = 0; c < 16; ++c) acc[c] = 0.0f;
  #pragma unroll
  for (int k = 0; k < KTOP; ++k) {
    float wk = wgt[k];
    int p = bp[k];
    #pragma unroll
    for (int c = 0; c < 16; ++c)
      acc[c] += wk * sb[c * NPTS + p];       // L1/L2-hit gathers
  }

  float* ob = out + (((size_t)b * NCH + cg * 16) * IMG + h) * IMG + w;
  const int S = IMG * IMG;
  #pragma unroll
  for (int c = 0; c < 16; ++c)
    ob[c * S] = acc[c];                      // coalesced over lanes (w)
}

extern "C" void kernel_launch(void* const* d_in, const int* in_sizes, int n_in,
                              void* d_out, int out_size, void* d_ws, size_t ws_size,
                              hipStream_t stream) {
  const float* pts = (const float*)d_in[0];   // [B,P,3]
  const float* src = (const float*)d_in[1];   // [B,C,P]
  float* out = (float*)d_out;                 // [B,C,H,W]

  raster_mega<<<BATCH * IMG * 2 * 4, 64, 0, stream>>>(pts, src, out);
}